// Round 1
// baseline (185.328 us; speedup 1.0000x reference)
//
#include <hip/hip_runtime.h>
#include <hip/hip_bf16.h>

// STDP: delta_w[q,p] = 4*w*(1-w) * (A/B) * sum_k AT[q][k]*BT[p][k]
//   AT[q][ b*128+t        ] = post_spikes[b][t][q]
//   AT[q][ 2048 + b*128+t ] = post_trace [b][t][q]
//   BT[p][ b*128+t        ] = pre_trace  [b][t][p]
//   BT[p][ 2048 + b*128+t ] = -pre_spikes[b][t][p]

typedef __attribute__((ext_vector_type(8))) short bf16x8;
typedef __attribute__((ext_vector_type(4))) float f32x4;

#define GN 2048
#define GK 4096
#define A_SCALE (0.01f / 16.0f)

#define GLOAD_LDS16(gp, lp) \
    __builtin_amdgcn_global_load_lds((const __attribute__((address_space(1))) void*)(gp), \
                                     (__attribute__((address_space(3))) void*)(lp), 16, 0, 0)

// ---------------------------------------------------------------------------
// Kernel 1: per-(b, n-slab) scan: compute exp-decay trace, cast to bf16,
// transpose through LDS, write AT/BT rows (k-contiguous).
// grid (32, 16, 2), block 64.  z=0: post -> AT, z=1: pre -> BT
// ---------------------------------------------------------------------------
__global__ __launch_bounds__(64) void trace_kernel(
    const float* __restrict__ pre,
    const float* __restrict__ post,
    const int* __restrict__ dtp,
    __hip_bfloat16* __restrict__ AT,
    __hip_bfloat16* __restrict__ BT)
{
    const int tid = threadIdx.x;
    const int n0  = blockIdx.x * 64;
    const int b   = blockIdx.y;
    const int a   = blockIdx.z;

    // dt is a python scalar; harness should give int32, hedge for float32 bits
    int di = dtp[0];
    float dtf = (di > 0 && di < 1000000) ? (float)di : *(const float*)dtp;
    const float decay = __expf(-dtf / 20.0f);

    __shared__ __hip_bfloat16 lds_sp[64][130];  // 130 pad: stride 260B -> conflict-free
    __shared__ __hip_bfloat16 lds_tr[64][130];

    const float* src = (a == 0) ? post : pre;
    const float  sgn = (a == 0) ? 1.0f : -1.0f;
    const int n = n0 + tid;

    float tr = 0.0f;
    #pragma unroll 4
    for (int t = 0; t < 128; ++t) {
        float s = src[((size_t)b * 128 + t) * GN + n];
        if (t > 0) tr = decay * tr + s;  // trace[0] = 0, spikes[0] unused in trace
        lds_sp[tid][t] = __float2bfloat16(s * sgn);
        lds_tr[tid][t] = __float2bfloat16(tr);
    }
    __syncthreads();

    // a=0: first half <- spikes(+), second <- trace
    // a=1: first half <- trace,     second <- spikes(-)
    const __hip_bfloat16 (*first)[130]  = (a == 0) ? lds_sp : lds_tr;
    const __hip_bfloat16 (*second)[130] = (a == 0) ? lds_tr : lds_sp;
    __hip_bfloat16* dst = (a == 0) ? AT : BT;

    for (int r = 0; r < 64; ++r) {
        unsigned int v1 = *(const unsigned int*)&first[r][2 * tid];
        unsigned int v2 = *(const unsigned int*)&second[r][2 * tid];
        unsigned int* row1 = (unsigned int*)(dst + (size_t)(n0 + r) * GK + b * 128);
        unsigned int* row2 = (unsigned int*)(dst + (size_t)(n0 + r) * GK + 2048 + b * 128);
        row1[tid] = v1;   // 64 lanes x 4B = 256B coalesced
        row2[tid] = v2;
    }
}

// ---------------------------------------------------------------------------
// Kernel 2: C = AT * BT^T (both [2048][4096] bf16, k-contiguous rows),
// 128x128 tile, BK=64, 4 waves of 64x64, mfma 16x16x32 bf16,
// global_load_lds(16B) staging with XOR k-chunk swizzle on the SOURCE side
// (LDS dest is forced to base + lane*16).
// grid (16,16), block 256.
// ---------------------------------------------------------------------------
__global__ __launch_bounds__(256) void stdp_gemm(
    const __hip_bfloat16* __restrict__ AT,
    const __hip_bfloat16* __restrict__ BT,
    const float* __restrict__ W,
    float* __restrict__ out)
{
    __shared__ alignas(16) __hip_bfloat16 As[128 * 64];
    __shared__ alignas(16) __hip_bfloat16 Bs[128 * 64];

    const int tid  = threadIdx.x;
    const int lane = tid & 63;
    const int wv   = tid >> 6;          // wave 0..3
    const int wm   = (wv >> 1) * 64;    // wave's m offset in tile
    const int wn   = (wv & 1) * 64;
    const int RM   = blockIdx.y * 128;  // q base
    const int CN   = blockIdx.x * 128;  // p base
    const int l15  = lane & 15;
    const int quad = lane >> 4;         // 0..3

    f32x4 acc[4][4] = {};

    for (int k0 = 0; k0 < GK; k0 += 64) {
        __syncthreads();  // previous iter's ds_reads done before overwrite
        #pragma unroll
        for (int it = 0; it < 4; ++it) {
            const int cbase = it * 256 + wv * 64;      // wave-uniform chunk base
            const int c     = cbase + lane;            // 16B chunk id, 0..1023
            const int row   = c >> 3;                  // tile row (8 chunks/row)
            const int kc    = (c & 7) ^ (row & 7);     // XOR swizzle (self-inverse)
            const __hip_bfloat16* ga = AT + (size_t)(RM + row) * GK + k0 + kc * 8;
            const __hip_bfloat16* gb = BT + (size_t)(CN + row) * GK + k0 + kc * 8;
            GLOAD_LDS16(ga, As + (size_t)cbase * 8);
            GLOAD_LDS16(gb, Bs + (size_t)cbase * 8);
        }
        __syncthreads();  // vmcnt(0) drain: staged data visible

        #pragma unroll
        for (int kk = 0; kk < 64; kk += 32) {
            const int jg = (kk >> 3) + quad;  // global k-chunk 0..3 / 4..7
            bf16x8 af[4], bfr[4];
            #pragma unroll
            for (int i = 0; i < 4; ++i) {
                const int mr = wm + i * 16 + l15;
                af[i]  = *(const bf16x8*)(As + mr * 64 + ((jg ^ (mr & 7)) * 8));
                const int nr = wn + i * 16 + l15;
                bfr[i] = *(const bf16x8*)(Bs + nr * 64 + ((jg ^ (nr & 7)) * 8));
            }
            #pragma unroll
            for (int i = 0; i < 4; ++i)
                #pragma unroll
                for (int j = 0; j < 4; ++j)
                    acc[i][j] = __builtin_amdgcn_mfma_f32_16x16x32_bf16(
                        af[i], bfr[j], acc[i][j], 0, 0, 0);
        }
    }

    // epilogue: C/D layout col = lane&15, row = quad*4 + reg   (m89-verified)
    #pragma unroll
    for (int i = 0; i < 4; ++i) {
        #pragma unroll
        for (int r = 0; r < 4; ++r) {
            const int q = RM + wm + i * 16 + quad * 4 + r;
            #pragma unroll
            for (int j = 0; j < 4; ++j) {
                const int p = CN + wn + j * 16 + l15;
                const float w  = W[(size_t)q * GN + p];
                const float wf = 4.0f * w * (1.0f - w);
                out[(size_t)q * GN + p] = wf * A_SCALE * acc[i][j][r];
            }
        }
    }
}

extern "C" void kernel_launch(void* const* d_in, const int* in_sizes, int n_in,
                              void* d_out, int out_size, void* d_ws, size_t ws_size,
                              hipStream_t stream) {
    const float* W    = (const float*)d_in[0];  // [2048][2048]
    const float* pre  = (const float*)d_in[1];  // [16][128][2048]
    const float* post = (const float*)d_in[2];  // [16][128][2048]
    const int*   dt   = (const int*)d_in[3];
    float* out = (float*)d_out;

    __hip_bfloat16* AT = (__hip_bfloat16*)d_ws;            // 2048*4096*2 = 16 MB
    __hip_bfloat16* BT = AT + (size_t)GN * GK;             // +16 MB (ws >= 32 MB)

    trace_kernel<<<dim3(32, 16, 2), 64, 0, stream>>>(pre, post, dt, AT, BT);
    stdp_gemm<<<dim3(16, 16), 256, 0, stream>>>(AT, BT, W, out);
}